// Round 11
// baseline (320.225 us; speedup 1.0000x reference)
//
#include <hip/hip_runtime.h>
#include <stdint.h>

// EETQLinear w8a16: out[m,n] = (sum_k x[m,k]*wq[k,n]) * scale[n] + bias[n]
// M=8192, K=4096, N=4096. Dtypes (r3/r4-verified): x/scale/bias/out f32, wq int32.
// v11: TWO BLOCKS PER CU (independent barrier groups -> cross-block MFMA/LDS
//      overlap). Tile 128x256, 8 waves (2Mx4N, 64x64 out, acc=64 AGPR), BK=32,
//      2 LDS buffers (48KB/block), 1 barrier/K-tile, vmcnt(0) on a 1-tile stage
//      lead, r10-verified 64B-row swizzle (0 conflicts). __launch_bounds__(512,4).

typedef __attribute__((ext_vector_type(4))) float     f32x4;
typedef __attribute__((ext_vector_type(8))) _Float16  f16x8;

#define M_DIM 8192
#define N_DIM 4096
#define K_DIM 4096

// ---------------- prologue kernels (r4-verified) ----------------
__global__ __launch_bounds__(256) void convert_x_to_f16(const float* __restrict__ x,
                                                        _Float16* __restrict__ Xh) {
    const size_t i = ((size_t)blockIdx.x * 256 + threadIdx.x) * 8;
    float4 v0 = *(const float4*)(x + i);
    float4 v1 = *(const float4*)(x + i + 4);
    f16x8 h;
    h[0] = (_Float16)v0.x; h[1] = (_Float16)v0.y; h[2] = (_Float16)v0.z; h[3] = (_Float16)v0.w;
    h[4] = (_Float16)v1.x; h[5] = (_Float16)v1.y; h[6] = (_Float16)v1.z; h[7] = (_Float16)v1.w;
    *(f16x8*)(Xh + i) = h;
}

__global__ __launch_bounds__(256) void dequant_w_to_f16(const int* __restrict__ wq,
                                                        _Float16* __restrict__ Wt) {
    __shared__ _Float16 tile[64][65];
    const int n0 = blockIdx.x * 64;
    const int k0 = blockIdx.y * 64;
    const int t  = threadIdx.x;
    const int r  = t >> 2;
    const int c0 = (t & 3) * 16;
    const int* src = wq + (size_t)(k0 + r) * N_DIM + n0 + c0;
#pragma unroll
    for (int j = 0; j < 4; ++j) {
        int4 q = *(const int4*)(src + j * 4);
        tile[c0 + j * 4 + 0][r] = (_Float16)q.x;
        tile[c0 + j * 4 + 1][r] = (_Float16)q.y;
        tile[c0 + j * 4 + 2][r] = (_Float16)q.z;
        tile[c0 + j * 4 + 3][r] = (_Float16)q.w;
    }
    __syncthreads();
    const int nn  = t >> 2;
    const int cc0 = (t & 3) * 16;
    _Float16 vals[16] __attribute__((aligned(16)));
#pragma unroll
    for (int j = 0; j < 16; ++j) vals[j] = tile[nn][cc0 + j];
    _Float16* dst = Wt + (size_t)(n0 + nn) * K_DIM + k0 + cc0;
    *(float4*)(dst + 0) = *(const float4*)(vals + 0);
    *(float4*)(dst + 8) = *(const float4*)(vals + 8);
}

// ---------------- 128x256 2-blocks/CU GEMM ----------------
#define AS1C(p) (const __attribute__((address_space(1))) void*)(p)
#define AS3C(p) (__attribute__((address_space(3))) void*)(p)

// stage K-tile tl into buffer at byte offset BB: A (8KB) then B (16KB). Linear
// LDS dest (t*16); source slot pre-XOR-swizzled (rule 21, r10-verified).
#define STAGE(BB, tl) do {                                                            \
    __builtin_amdgcn_global_load_lds(AS1C(aStageBase + (size_t)(tl) * 32),            \
        AS3C(ldsBase + (BB) + t * 16), 16, 0, 0);                                     \
    __builtin_amdgcn_global_load_lds(AS1C(bStageBase + (size_t)(tl) * 32),            \
        AS3C(ldsBase + (BB) + 8192 + t * 16), 16, 0, 0);                              \
    __builtin_amdgcn_global_load_lds(AS1C(bStageBase + bHalfJump + (size_t)(tl) * 32),\
        AS3C(ldsBase + (BB) + 16384 + t * 16), 16, 0, 0);                             \
} while (0)

#define DSR(dst, addr, IMM) \
    asm volatile("ds_read_b128 %0, %1 offset:%c2" : "=v"(dst) : "v"(addr), "i"(IMM))

// 8 fragment reads of the buffer at imm offset IB (0 or 24576)
#define READS(IB)                    \
    DSR(a0, aAddr, (IB) + 0);        \
    DSR(a1, aAddr, (IB) + 1024);     \
    DSR(a2, aAddr, (IB) + 2048);     \
    DSR(a3, aAddr, (IB) + 3072);     \
    DSR(b0, bAddr, (IB) + 0);        \
    DSR(b1, bAddr, (IB) + 1024);     \
    DSR(b2, bAddr, (IB) + 2048);     \
    DSR(b3, bAddr, (IB) + 3072)

#define MM(AI, NI, AV, BV) \
    acc[AI][NI] = __builtin_amdgcn_mfma_f32_16x16x32_f16(AV, BV, acc[AI][NI], 0, 0, 0)

#define MFMA16()                                                            \
    MM(0, 0, a0, b0); MM(0, 1, a0, b1); MM(0, 2, a0, b2); MM(0, 3, a0, b3); \
    MM(1, 0, a1, b0); MM(1, 1, a1, b1); MM(1, 2, a1, b2); MM(1, 3, a1, b3); \
    MM(2, 0, a2, b0); MM(2, 1, a2, b1); MM(2, 2, a2, b2); MM(2, 3, a2, b3); \
    MM(3, 0, a3, b0); MM(3, 1, a3, b1); MM(3, 2, a3, b2); MM(3, 3, a3, b3)

#define BARR()  __builtin_amdgcn_s_barrier()
#define SB0()   __builtin_amdgcn_sched_barrier(0)
#define LGKM0() do { asm volatile("s_waitcnt lgkmcnt(0)" ::: "memory"); SB0(); } while (0)
#define VMC0()  asm volatile("s_waitcnt vmcnt(0)" ::: "memory")
#define PRIO1() __builtin_amdgcn_s_setprio(1)
#define PRIO0() __builtin_amdgcn_s_setprio(0)

// One K-tile: wait my stage of THIS tile (only thing in flight), barrier
// broadcasts "landed"; stage next tile into the buffer whose reads all waves
// finished before arriving here (race-free: each wave's LGKM0 of tile i-1
// precedes its BARR(i)); read 8 frags; 16 MFMA.
#define KTILE(IB_RD, BB_ST, tl) do {                                                  \
    VMC0(); BARR();                                                                   \
    STAGE(BB_ST, tl);                                                                 \
    READS(IB_RD);                                                                     \
    LGKM0(); PRIO1(); MFMA16(); PRIO0();                                              \
} while (0)

__global__ __launch_bounds__(512, 4) void gemm_2b(const _Float16* __restrict__ Xh,
                                                  const _Float16* __restrict__ Wt,
                                                  const float* __restrict__ scale,
                                                  const float* __restrict__ bias,
                                                  float* __restrict__ C) {
    // 2 buffers x 24KB: [A 128x32 (8KB) | B 256x32 (16KB)], rows of 64B
    __shared__ __attribute__((aligned(128))) _Float16 L[24576];   // 48 KB
    char* ldsBase = (char*)L;

    // T1: XCD-aware bijective swizzle (1024 blocks, 1024 % 8 == 0)
    const int bid = blockIdx.x;
    const int swz = (bid & 7) * 128 + (bid >> 3);
    const int bm  = swz >> 4;            // 0..63  (M / 128)
    const int bn  = swz & 15;            // 0..15  (N / 256)

    const int t  = threadIdx.x;          // 0..511
    const int l  = t & 63;
    const int w  = t >> 6;               // 8 waves: 2(M) x 4(N)
    const int wm = w >> 2, wn = w & 3;   // wave out: 64 rows x 64 cols
    const int lr = l & 15, lh = l >> 4;

    // staging: thread t owns row t>>2 (A; B rows t>>2 and t>>2+128), slot t&3.
    // Source slot pre-XORed by ((row>>1)&3) = ((t>>3)&3)  [r10-verified, 0 conf]
    const int rowIdx = t >> 2;                                  // 0..127
    const int kb     = ((t & 3) ^ ((t >> 3) & 3)) * 8;          // elems
    const _Float16* aStageBase = Xh + (size_t)(bm * 128 + rowIdx) * K_DIM + kb;
    const _Float16* bStageBase = Wt + (size_t)(bn * 256 + rowIdx) * K_DIM + kb;
    const size_t bHalfJump = (size_t)128 * K_DIM;

    // ds_read lane addresses (r10-verified pattern): byte = row*64 + xr, frags
    // at +mi*1024 (16 rows), buf1 at +24576 imm. A at 0, B section at +8192.
    const uint32_t xr = (uint32_t)((lh ^ ((lr >> 1) & 3)) << 4);
    const uint32_t aAddr = (uint32_t)(uintptr_t)L + (uint32_t)((wm * 64 + lr) * 64) + xr;
    const uint32_t bAddr = (uint32_t)(uintptr_t)L + 8192u
                         + (uint32_t)((wn * 64 + lr) * 64) + xr;

    f16x8 a0, a1, a2, a3, b0, b1, b2, b3;
    f32x4 acc[4][4] = {};

    // prologue: stage K-tile 0 into buf0 (3 DMA/thread outstanding)
    STAGE(0, 0);

#pragma unroll 1
    for (int j = 0; j < K_DIM / 64; ++j) {        // 128 K-tiles, 2 per iteration
        const int te = 2 * j + 1;                 // tile staged during even slot
        const int to = (2 * j + 2) & 127;         // tile staged during odd slot (wraps last)
        KTILE(0,     24576, te);                  // read buf0, stage te -> buf1
        KTILE(24576, 0,     to);                  // read buf1, stage to -> buf0
    }
    VMC0();                                        // drain dangling prefetch

    // epilogue: C/D layout col = lane&15, row = (lane>>4)*4 + reg  [m89-verified]
    const int col0 = bn * 256 + wn * 64 + lr;
    const int row0 = bm * 128 + wm * 64 + lh * 4;
    float sc[4], bi[4];
#pragma unroll
    for (int ni = 0; ni < 4; ++ni) {
        sc[ni] = scale[col0 + ni * 16];
        bi[ni] = bias[col0 + ni * 16];
    }
#pragma unroll
    for (int mi = 0; mi < 4; ++mi)
#pragma unroll
        for (int r = 0; r < 4; ++r) {
            const size_t rowOff = (size_t)(row0 + mi * 16 + r) * N_DIM;
#pragma unroll
            for (int ni = 0; ni < 4; ++ni)
                C[rowOff + col0 + ni * 16] = acc[mi][ni][r] * sc[ni] + bi[ni];
        }
}

extern "C" void kernel_launch(void* const* d_in, const int* in_sizes, int n_in,
                              void* d_out, int out_size, void* d_ws, size_t ws_size,
                              hipStream_t stream) {
    const float* x     = (const float*)d_in[0];
    const int*   wq    = (const int*)d_in[1];
    const float* scale = (const float*)d_in[2];
    const float* bias  = (const float*)d_in[3];
    float* out = (float*)d_out;

    const size_t needW = (size_t)N_DIM * K_DIM * sizeof(_Float16);   // 33.5 MB
    _Float16* Wt = (_Float16*)d_ws;
    _Float16* Xh = (_Float16*)((char*)d_ws + needW);                 // ws >= 100.7MB (r4)

    dim3 tgrid(N_DIM / 64, K_DIM / 64);
    dequant_w_to_f16<<<tgrid, 256, 0, stream>>>(wq, Wt);
    convert_x_to_f16<<<((size_t)M_DIM * K_DIM) / (256 * 8), 256, 0, stream>>>(x, Xh);

    const int nblocks = (M_DIM / 128) * (N_DIM / 256);               // 1024
    gemm_2b<<<nblocks, 512, 0, stream>>>(Xh, Wt, scale, bias, out);
}